// Round 2
// baseline (5682.894 us; speedup 1.0000x reference)
//
#include <hip/hip_runtime.h>

// DRL4TSP pointer-network decode. B=1024, S=2, D=1, H=128, N=128.
// Key algebra: static_enc is rank-2+bias in h, dynamic_enc rank-1+bias.
// All big per-step GEMMs collapse to precomputed H-vectors + per-step
// matvecs (w_hh@h, A3@h) + two HxN tanh-dot loops.
//
// Numerics: argmax-feeding paths use libm-accurate tanhf/expf/logf and IEEE
// division to minimize deviation from the JAX reference (argmax flips cascade).
// Fast-math variants are a later, counter-verified A/B.

#define H128 128
#define N128 128
#define B1024 1024

__device__ __forceinline__ float sigmoid_acc(float x){
    return 1.f / (1.f + expf(-x));
}

// ---------------- prep: fold rank structure into packed tables ----------------
// ws layout (floats): A4[128]@0, D4[128]@512, Q4[128]@1024, G4[384]@1536  (total 3072)
// A4[h] = {u0, u1, u2, attn_v[h]}            (attn score tables)
// D4[h] = {v0, v1, dec_v[h], 0}              (dec score tables)
// Q4[h] = {q0, q1, c2sum, c1}                (ctx-fold + constants)
// G4[j] = {g0, g1, gc, b_hh[j]}  j<384       (GRU input-fold + b_hh)
__global__ void prep_kernel(const float* __restrict__ enc_s_w, const float* __restrict__ enc_s_b,
                            const float* __restrict__ enc_d_w, const float* __restrict__ enc_d_b,
                            const float* __restrict__ emb_w,   const float* __restrict__ emb_b,
                            const float* __restrict__ w_ih,    const float* __restrict__ b_ih,
                            const float* __restrict__ b_hh,
                            const float* __restrict__ attn_v,  const float* __restrict__ attn_W,
                            const float* __restrict__ dec_v,   const float* __restrict__ dec_W,
                            float4* __restrict__ A4, float4* __restrict__ D4,
                            float4* __restrict__ Q4, float4* __restrict__ G4)
{
    const int tid = threadIdx.x;
    const int blk = blockIdx.x;
    if (blk < 3){
        // G4 row j = blk*128+tid : g0 = w_ih[j,:]@emb_w[:,0], g1 = ..[:,1], gc = w_ih@emb_b + b_ih
        const int j = blk*128 + tid;
        const float* w = w_ih + j*H128;
        float a = 0.f, b = 0.f, c = 0.f;
        for (int k = 0; k < H128; ++k){
            float wv = w[k];
            a = fmaf(wv, emb_w[2*k],   a);
            b = fmaf(wv, emb_w[2*k+1], b);
            c = fmaf(wv, emb_b[k],     c);
        }
        G4[j] = make_float4(a, b, c + b_ih[j], b_hh[j]);
    } else {
        const int h = tid;
        // attn: A1 = attn_W[:,0:128] (static), A2 = [:,128:256] (dynamic)
        const float* aw = attn_W + h*384;
        float u0=0.f, u1=0.f, u2=0.f, c1=0.f;
        for (int k = 0; k < H128; ++k){
            float w = aw[k];
            u0 = fmaf(w, enc_s_w[2*k],   u0);
            u1 = fmaf(w, enc_s_w[2*k+1], u1);
            c1 = fmaf(w, enc_s_b[k],     c1);
        }
        for (int k = 0; k < H128; ++k){
            float w = aw[128+k];
            u2 = fmaf(w, enc_d_w[k], u2);
            c1 = fmaf(w, enc_d_b[k], c1);
        }
        A4[h] = make_float4(u0, u1, u2, attn_v[h]);
        // dec: D1 = dec_W[:,0:128] (static part), D2 = [:,128:256] (ctx part)
        const float* dw = dec_W + h*256;
        float v0=0.f, v1=0.f, c2=0.f, q0=0.f, q1=0.f;
        for (int k = 0; k < H128; ++k){
            float w = dw[k];
            v0 = fmaf(w, enc_s_w[2*k],   v0);
            v1 = fmaf(w, enc_s_w[2*k+1], v1);
            c2 = fmaf(w, enc_s_b[k],     c2);
        }
        for (int k = 0; k < H128; ++k){
            float w = dw[128+k];
            q0 = fmaf(w, enc_s_w[2*k],   q0);
            q1 = fmaf(w, enc_s_w[2*k+1], q1);
            c2 = fmaf(w, enc_s_b[k],     c2);   // ctx bias == enc_s_b (sum attn == 1)
        }
        D4[h] = make_float4(v0, v1, dec_v[h], 0.f);
        Q4[h] = make_float4(q0, q1, c2, c1);
    }
}

// ---------------- main decode: one block = 2 batches, 256 threads ----------------
__global__ __launch_bounds__(256, 2)
void decode_kernel(const float* __restrict__ statc, const float* __restrict__ dyn,
                   const float* __restrict__ x0,    const float* __restrict__ whh,
                   const float* __restrict__ attnW,
                   const float4* __restrict__ A4g, const float4* __restrict__ D4g,
                   const float4* __restrict__ Q4g, const float4* __restrict__ G4g,
                   float* __restrict__ out)
{
    __shared__ __align__(16) float hbuf[2][H128];
    __shared__ float s0l[2][N128], s1l[2][N128];
    __shared__ float ahl[2][H128], chl[2][H128];
    __shared__ float lo[2][2];
    __shared__ float red[2][2][8];
    __shared__ __align__(16) float4 A4s[H128], D4s[H128];

    const int tid = threadIdx.x;
    const int g   = tid >> 7;         // which of the 2 batches in this block
    const int jl  = tid & 127;        // h-row / n-column owned by this thread
    const int wv  = (tid >> 6) & 1;   // wave within the g-half
    const int b   = blockIdx.x*2 + g;

    if (tid < 128) A4s[tid] = A4g[tid];
    else           D4s[tid-128] = D4g[tid-128];

    const float4 qv = Q4g[jl];
    const float q0r = qv.x, q1r = qv.y, c2r = qv.z, c1r = qv.w;
    const float4 Gr = G4g[jl], Gz = G4g[jl+128], Gn = G4g[jl+256];

    const float s0n = statc[b*256 + jl];
    const float s1n = statc[b*256 + 128 + jl];
    const float d0n = dyn[b*128 + jl];
    s0l[g][jl] = s0n; s1l[g][jl] = s1n;
    hbuf[g][jl] = 0.f;
    float hreg = 0.f;
    if (jl == 0){ lo[g][0] = x0[0]; lo[g][1] = x0[1]; }

    const float4* wr4 = (const float4*)(whh + jl*H128);            // w_hh r-gate row
    const float4* wz4 = (const float4*)(whh + (jl+128)*H128);      // z-gate row
    const float4* wn4 = (const float4*)(whh + (jl+256)*H128);      // n-gate row
    const float4* a34 = (const float4*)(attnW + jl*384 + 256);     // A3 row jl
    const float4* hv4 = (const float4*)(&hbuf[g][0]);

    float logp = 0.f;
    __syncthreads();

    for (int t = 0; t < N128; ++t){
        // ---- phase 1: GRU (gh = w_hh@h, gi folded to 2 scalars) ----
        float lo0 = lo[g][0], lo1 = lo[g][1];
        float accr = 0.f, accz = 0.f, accn = 0.f;
        #pragma unroll 4
        for (int k = 0; k < 32; ++k){
            float4 hv = hv4[k];
            float4 w0 = wr4[k], w1 = wz4[k], w2 = wn4[k];
            accr = fmaf(w0.x,hv.x, fmaf(w0.y,hv.y, fmaf(w0.z,hv.z, fmaf(w0.w,hv.w, accr))));
            accz = fmaf(w1.x,hv.x, fmaf(w1.y,hv.y, fmaf(w1.z,hv.z, fmaf(w1.w,hv.w, accz))));
            accn = fmaf(w2.x,hv.x, fmaf(w2.y,hv.y, fmaf(w2.z,hv.z, fmaf(w2.w,hv.w, accn))));
        }
        float gir = fmaf(Gr.x, lo0, fmaf(Gr.y, lo1, Gr.z));
        float giz = fmaf(Gz.x, lo0, fmaf(Gz.y, lo1, Gz.z));
        float gin = fmaf(Gn.x, lo0, fmaf(Gn.y, lo1, Gn.z));
        float r  = sigmoid_acc(gir + (accr + Gr.w));
        float z  = sigmoid_acc(giz + (accz + Gz.w));
        float nn = tanhf(gin + r * (accn + Gn.w));
        float hnew = (1.f - z) * nn + z * hreg;
        __syncthreads();                 // all reads of old h done
        hbuf[g][jl] = hnew; hreg = hnew;
        __syncthreads();
        // ---- phase 2: ah = A3@h + c1 ----
        float acc = c1r;
        #pragma unroll 4
        for (int k = 0; k < 32; ++k){
            float4 hv = hv4[k]; float4 w = a34[k];
            acc = fmaf(w.x,hv.x, fmaf(w.y,hv.y, fmaf(w.z,hv.z, fmaf(w.w,hv.w, acc))));
        }
        ahl[g][jl] = acc;
        __syncthreads();
        // ---- phase 3: attention scores (thread = column n) ----
        float sc = 0.f;
        #pragma unroll 4
        for (int h = 0; h < H128; ++h){
            float4 a = A4s[h];
            float tt = fmaf(a.x, s0n, fmaf(a.y, s1n, fmaf(a.z, d0n, ahl[g][h])));
            sc = fmaf(tanhf(tt), a.w, sc);
        }
        float m = sc;
        #pragma unroll
        for (int off = 32; off > 0; off >>= 1) m = fmaxf(m, __shfl_xor(m, off, 64));
        if ((tid & 63) == 0) red[g][wv][0] = m;
        __syncthreads();
        m = fmaxf(red[g][0][0], red[g][1][0]);
        float e  = expf(sc - m);
        float se = e, sa = e * s0n, sb = e * s1n;   // softmax denom + attn@s0 + attn@s1
        #pragma unroll
        for (int off = 32; off > 0; off >>= 1){
            se += __shfl_xor(se, off, 64);
            sa += __shfl_xor(sa, off, 64);
            sb += __shfl_xor(sb, off, 64);
        }
        if ((tid & 63) == 0){ red[g][wv][1] = se; red[g][wv][2] = sa; red[g][wv][3] = sb; }
        __syncthreads();
        float ssum = red[g][0][1] + red[g][1][1];
        float cs0 = (red[g][0][2] + red[g][1][2]) / ssum;
        float cs1 = (red[g][0][3] + red[g][1][3]) / ssum;
        chl[g][jl] = fmaf(q0r, cs0, fmaf(q1r, cs1, c2r));   // dec_W2@context fold
        __syncthreads();
        // ---- phase 4: decoder scores + argmax + logsumexp ----
        float lg = 0.f;
        #pragma unroll 4
        for (int h = 0; h < H128; ++h){
            float4 dd = D4s[h];
            float tt = fmaf(dd.x, s0n, fmaf(dd.y, s1n, chl[g][h]));
            lg = fmaf(tanhf(tt), dd.z, lg);
        }
        float v = lg; int bi = jl;
        #pragma unroll
        for (int off = 32; off > 0; off >>= 1){       // first-index tie-break == jnp.argmax
            float ov = __shfl_xor(v, off, 64);
            int   oi = __shfl_xor(bi, off, 64);
            if (ov > v || (ov == v && oi < bi)){ v = ov; bi = oi; }
        }
        if ((tid & 63) == 0){ red[g][wv][4] = v; red[g][wv][5] = __int_as_float(bi); }
        __syncthreads();
        float va = red[g][0][4], vb = red[g][1][4];
        int   ia = __float_as_int(red[g][0][5]), ib = __float_as_int(red[g][1][5]);
        float m2; int ptr;
        if (va > vb || (va == vb && ia < ib)){ m2 = va; ptr = ia; } else { m2 = vb; ptr = ib; }
        float e2 = expf(lg - m2);
        #pragma unroll
        for (int off = 32; off > 0; off >>= 1) e2 += __shfl_xor(e2, off, 64);
        if ((tid & 63) == 0) red[g][wv][6] = e2;
        __syncthreads();
        float sum2 = red[g][0][6] + red[g][1][6];
        logp -= logf(sum2);                 // log(max prob) = -log(sum exp(l-m))
        if (jl == 0){
            out[b*N128 + t] = (float)ptr;   // tour_idx as float
            lo[g][0] = s0l[g][ptr];         // last_out = static[b,:,ptr]
            lo[g][1] = s1l[g][ptr];
        }
        __syncthreads();
    }
    if (jl == 0) out[B1024*N128 + b] = logp;
}

extern "C" void kernel_launch(void* const* d_in, const int* in_sizes, int n_in,
                              void* d_out, int out_size, void* d_ws, size_t ws_size,
                              hipStream_t stream)
{
    const float* statc   = (const float*)d_in[0];
    const float* dyn     = (const float*)d_in[1];
    const float* enc_s_w = (const float*)d_in[2];
    const float* enc_s_b = (const float*)d_in[3];
    const float* enc_d_w = (const float*)d_in[4];
    const float* enc_d_b = (const float*)d_in[5];
    const float* x0      = (const float*)d_in[6];
    const float* emb_w   = (const float*)d_in[7];
    const float* emb_b   = (const float*)d_in[8];
    const float* w_ih    = (const float*)d_in[9];
    const float* w_hh    = (const float*)d_in[10];
    const float* b_ih    = (const float*)d_in[11];
    const float* b_hh    = (const float*)d_in[12];
    const float* attn_v  = (const float*)d_in[13];
    const float* attn_W  = (const float*)d_in[14];
    const float* dec_v   = (const float*)d_in[15];
    const float* dec_W   = (const float*)d_in[16];

    float* ws = (float*)d_ws;
    float4* A4 = (float4*)(ws);
    float4* D4 = (float4*)(ws + 512);
    float4* Q4 = (float4*)(ws + 1024);
    float4* G4 = (float4*)(ws + 1536);

    prep_kernel<<<dim3(4), dim3(128), 0, stream>>>(
        enc_s_w, enc_s_b, enc_d_w, enc_d_b, emb_w, emb_b,
        w_ih, b_ih, b_hh, attn_v, attn_W, dec_v, dec_W,
        A4, D4, Q4, G4);

    decode_kernel<<<dim3(B1024/2), dim3(256), 0, stream>>>(
        statc, dyn, x0, w_hh, attn_W,
        A4, D4, Q4, G4, (float*)d_out);
}

// Round 3
// 4979.144 us; speedup vs baseline: 1.1413x; 1.1413x over previous
//
#include <hip/hip_runtime.h>

// DRL4TSP pointer-network decode. B=1024, S=2, D=1, H=128, N=128.
// Rank-collapse algebra: static_enc rank-2+bias, dynamic_enc rank-1+bias =>
// all per-step GEMMs become precomputed H-vectors + w_hh@h, A3@h matvecs +
// two HxN tanh-dot loops.
//
// R2: GRU path keeps libm numerics (h trajectory bitwise identical to the
// validated R1 kernel). Score loops switch to branch-free fast tanh
// (1 - 2/(exp2(2log2e*x)+1), ~2e-7 abs err) -- libm tanhf diverges per-lane
// on its |x|<0.625 branch and dominated the issue stream. Barriers 9->5/step
// via h ping-pong, merged scaled reductions, and register last_out.

#define H128 128
#define N128 128
#define B1024 1024

__device__ __forceinline__ float sigmoid_acc(float x){
    return 1.f / (1.f + expf(-x));
}
// branch-free fast tanh; abs err ~2e-7, argmax-safe per R1 margin evidence
__device__ __forceinline__ float tanh_fast(float x){
    float xc = fminf(fmaxf(x, -10.f), 10.f);
    float e  = exp2f(xc * 2.885390081777927f);   // exp(2x): 1 mul + v_exp_f32
    return 1.f - __fdividef(2.f, e + 1.f);       // add, v_rcp, mul, sub
}

// ---------------- prep: fold rank structure into packed tables ----------------
// ws layout (floats): A4[128]@0, D4[128]@512, Q4[128]@1024, G4[384]@1536
// A4[h] = {u0, u1, u2, attn_v[h]}   D4[h] = {v0, v1, dec_v[h], 0}
// Q4[h] = {q0, q1, c2sum, c1}       G4[j] = {g0, g1, gc, b_hh[j]}
__global__ void prep_kernel(const float* __restrict__ enc_s_w, const float* __restrict__ enc_s_b,
                            const float* __restrict__ enc_d_w, const float* __restrict__ enc_d_b,
                            const float* __restrict__ emb_w,   const float* __restrict__ emb_b,
                            const float* __restrict__ w_ih,    const float* __restrict__ b_ih,
                            const float* __restrict__ b_hh,
                            const float* __restrict__ attn_v,  const float* __restrict__ attn_W,
                            const float* __restrict__ dec_v,   const float* __restrict__ dec_W,
                            float4* __restrict__ A4, float4* __restrict__ D4,
                            float4* __restrict__ Q4, float4* __restrict__ G4)
{
    const int tid = threadIdx.x;
    const int blk = blockIdx.x;
    if (blk < 3){
        const int j = blk*128 + tid;
        const float* w = w_ih + j*H128;
        float a = 0.f, b = 0.f, c = 0.f;
        for (int k = 0; k < H128; ++k){
            float wv = w[k];
            a = fmaf(wv, emb_w[2*k],   a);
            b = fmaf(wv, emb_w[2*k+1], b);
            c = fmaf(wv, emb_b[k],     c);
        }
        G4[j] = make_float4(a, b, c + b_ih[j], b_hh[j]);
    } else {
        const int h = tid;
        const float* aw = attn_W + h*384;
        float u0=0.f, u1=0.f, u2=0.f, c1=0.f;
        for (int k = 0; k < H128; ++k){
            float w = aw[k];
            u0 = fmaf(w, enc_s_w[2*k],   u0);
            u1 = fmaf(w, enc_s_w[2*k+1], u1);
            c1 = fmaf(w, enc_s_b[k],     c1);
        }
        for (int k = 0; k < H128; ++k){
            float w = aw[128+k];
            u2 = fmaf(w, enc_d_w[k], u2);
            c1 = fmaf(w, enc_d_b[k], c1);
        }
        A4[h] = make_float4(u0, u1, u2, attn_v[h]);
        const float* dw = dec_W + h*256;
        float v0=0.f, v1=0.f, c2=0.f, q0=0.f, q1=0.f;
        for (int k = 0; k < H128; ++k){
            float w = dw[k];
            v0 = fmaf(w, enc_s_w[2*k],   v0);
            v1 = fmaf(w, enc_s_w[2*k+1], v1);
            c2 = fmaf(w, enc_s_b[k],     c2);
        }
        for (int k = 0; k < H128; ++k){
            float w = dw[128+k];
            q0 = fmaf(w, enc_s_w[2*k],   q0);
            q1 = fmaf(w, enc_s_w[2*k+1], q1);
            c2 = fmaf(w, enc_s_b[k],     c2);   // ctx bias == enc_s_b (sum attn == 1)
        }
        D4[h] = make_float4(v0, v1, dec_v[h], 0.f);
        Q4[h] = make_float4(q0, q1, c2, c1);
    }
}

// ---------------- main decode: one block = 2 batches, 256 threads ----------------
__global__ __launch_bounds__(256, 2)
void decode_kernel(const float* __restrict__ statc, const float* __restrict__ dyn,
                   const float* __restrict__ x0,    const float* __restrict__ whh,
                   const float* __restrict__ attnW,
                   const float4* __restrict__ A4g, const float4* __restrict__ D4g,
                   const float4* __restrict__ Q4g, const float4* __restrict__ G4g,
                   float* __restrict__ out)
{
    __shared__ __align__(16) float hbuf[2][2][H128];      // [pingpong][g][h]
    __shared__ float s0l[2][N128], s1l[2][N128];
    __shared__ __align__(16) float ahl[2][H128], chl[2][H128];
    __shared__ float red[2][2][8];
    __shared__ __align__(16) float4 A4s[H128], D4s[H128];

    const int tid = threadIdx.x;
    const int g   = tid >> 7;         // batch within block
    const int jl  = tid & 127;        // h-row / n-column owned by this thread
    const int wv  = (tid >> 6) & 1;   // wave within the g-half
    const int b   = blockIdx.x*2 + g;

    if (tid < 128) A4s[tid] = A4g[tid];
    else           D4s[tid-128] = D4g[tid-128];

    const float4 qv = Q4g[jl];
    const float q0r = qv.x, q1r = qv.y, c2r = qv.z, c1r = qv.w;
    const float4 Gr = G4g[jl], Gz = G4g[jl+128], Gn = G4g[jl+256];

    const float s0n = statc[b*256 + jl];
    const float s1n = statc[b*256 + 128 + jl];
    const float d0n = dyn[b*128 + jl];
    s0l[g][jl] = s0n; s1l[g][jl] = s1n;
    hbuf[0][g][jl] = 0.f;
    float hreg = 0.f;
    float lo0 = x0[0], lo1 = x0[1];

    const float4* wr4 = (const float4*)(whh + jl*H128);            // w_hh r row
    const float4* wz4 = (const float4*)(whh + (jl+128)*H128);      // z row
    const float4* wn4 = (const float4*)(whh + (jl+256)*H128);      // n row
    const float4* a34 = (const float4*)(attnW + jl*384 + 256);     // A3 row jl

    float logp = 0.f;
    int cur = 0;
    __syncthreads();

    for (int t = 0; t < N128; ++t){
        // ---- phase 1: GRU (gh = w_hh@h; gi folded to 2 scalars). libm numerics.
        const float4* hv4 = (const float4*)&hbuf[cur][g][0];
        float accr = 0.f, accz = 0.f, accn = 0.f;
        #pragma unroll 4
        for (int k = 0; k < 32; ++k){
            float4 hv = hv4[k];
            float4 w0 = wr4[k], w1 = wz4[k], w2 = wn4[k];
            accr = fmaf(w0.x,hv.x, fmaf(w0.y,hv.y, fmaf(w0.z,hv.z, fmaf(w0.w,hv.w, accr))));
            accz = fmaf(w1.x,hv.x, fmaf(w1.y,hv.y, fmaf(w1.z,hv.z, fmaf(w1.w,hv.w, accz))));
            accn = fmaf(w2.x,hv.x, fmaf(w2.y,hv.y, fmaf(w2.z,hv.z, fmaf(w2.w,hv.w, accn))));
        }
        float gir = fmaf(Gr.x, lo0, fmaf(Gr.y, lo1, Gr.z));
        float giz = fmaf(Gz.x, lo0, fmaf(Gz.y, lo1, Gz.z));
        float gin = fmaf(Gn.x, lo0, fmaf(Gn.y, lo1, Gn.z));
        float r  = sigmoid_acc(gir + (accr + Gr.w));
        float z  = sigmoid_acc(giz + (accz + Gz.w));
        float nn = tanhf(gin + r * (accn + Gn.w));
        float hnew = (1.f - z) * nn + z * hreg;
        hbuf[cur^1][g][jl] = hnew; hreg = hnew;   // write other buffer: no pre-barrier
        __syncthreads();                           // B1: new h visible
        cur ^= 1;
        // ---- phase 2: ah = A3@h + c1
        const float4* hn4 = (const float4*)&hbuf[cur][g][0];
        float acc = c1r;
        #pragma unroll 4
        for (int k = 0; k < 32; ++k){
            float4 hv = hn4[k]; float4 w = a34[k];
            acc = fmaf(w.x,hv.x, fmaf(w.y,hv.y, fmaf(w.z,hv.z, fmaf(w.w,hv.w, acc))));
        }
        ahl[g][jl] = acc;
        __syncthreads();                           // B2: ahl visible
        // ---- phase 3: attention scores (thread = column n)
        const float4* ah4 = (const float4*)&ahl[g][0];
        float sc = 0.f;
        #pragma unroll 2
        for (int k = 0; k < 32; ++k){
            float4 ah = ah4[k];
            { float4 a = A4s[4*k+0]; float tt = fmaf(a.x,s0n, fmaf(a.y,s1n, fmaf(a.z,d0n, ah.x))); sc = fmaf(tanh_fast(tt), a.w, sc); }
            { float4 a = A4s[4*k+1]; float tt = fmaf(a.x,s0n, fmaf(a.y,s1n, fmaf(a.z,d0n, ah.y))); sc = fmaf(tanh_fast(tt), a.w, sc); }
            { float4 a = A4s[4*k+2]; float tt = fmaf(a.x,s0n, fmaf(a.y,s1n, fmaf(a.z,d0n, ah.z))); sc = fmaf(tanh_fast(tt), a.w, sc); }
            { float4 a = A4s[4*k+3]; float tt = fmaf(a.x,s0n, fmaf(a.y,s1n, fmaf(a.z,d0n, ah.w))); sc = fmaf(tanh_fast(tt), a.w, sc); }
        }
        // per-wave max + self-scaled partials, ONE barrier for the whole softmax
        float mw = sc;
        #pragma unroll
        for (int off = 32; off > 0; off >>= 1) mw = fmaxf(mw, __shfl_xor(mw, off, 64));
        float e  = __expf(sc - mw);
        float se = e, sa = e * s0n, sb = e * s1n;
        #pragma unroll
        for (int off = 32; off > 0; off >>= 1){
            se += __shfl_xor(se, off, 64);
            sa += __shfl_xor(sa, off, 64);
            sb += __shfl_xor(sb, off, 64);
        }
        if ((tid & 63) == 0){ red[g][wv][0]=mw; red[g][wv][1]=se; red[g][wv][2]=sa; red[g][wv][3]=sb; }
        __syncthreads();                           // B3: attn partials visible
        float m0 = red[g][0][0], m1 = red[g][1][0];
        float mm = fmaxf(m0, m1);
        float f0 = __expf(m0 - mm), f1 = __expf(m1 - mm);
        float ssum = fmaf(red[g][0][1], f0, red[g][1][1] * f1);
        float sat  = fmaf(red[g][0][2], f0, red[g][1][2] * f1);
        float sbt  = fmaf(red[g][0][3], f0, red[g][1][3] * f1);
        float cs0 = sat / ssum;
        float cs1 = sbt / ssum;
        chl[g][jl] = fmaf(q0r, cs0, fmaf(q1r, cs1, c2r));   // dec_W2@context fold
        __syncthreads();                           // B4: chl visible
        // ---- phase 4: decoder scores + argmax + logsumexp
        const float4* ch4 = (const float4*)&chl[g][0];
        float lg = 0.f;
        #pragma unroll 2
        for (int k = 0; k < 32; ++k){
            float4 ch = ch4[k];
            { float4 dd = D4s[4*k+0]; float tt = fmaf(dd.x,s0n, fmaf(dd.y,s1n, ch.x)); lg = fmaf(tanh_fast(tt), dd.z, lg); }
            { float4 dd = D4s[4*k+1]; float tt = fmaf(dd.x,s0n, fmaf(dd.y,s1n, ch.y)); lg = fmaf(tanh_fast(tt), dd.z, lg); }
            { float4 dd = D4s[4*k+2]; float tt = fmaf(dd.x,s0n, fmaf(dd.y,s1n, ch.z)); lg = fmaf(tanh_fast(tt), dd.z, lg); }
            { float4 dd = D4s[4*k+3]; float tt = fmaf(dd.x,s0n, fmaf(dd.y,s1n, ch.w)); lg = fmaf(tanh_fast(tt), dd.z, lg); }
        }
        float v = lg; int bi = jl;
        #pragma unroll
        for (int off = 32; off > 0; off >>= 1){   // first-index tie-break == jnp.argmax
            float ov = __shfl_xor(v, off, 64);
            int   oi = __shfl_xor(bi, off, 64);
            if (ov > v || (ov == v && oi < bi)){ v = ov; bi = oi; }
        }
        float e2 = __expf(lg - v);                 // all lanes hold wave max v
        #pragma unroll
        for (int off = 32; off > 0; off >>= 1) e2 += __shfl_xor(e2, off, 64);
        if ((tid & 63) == 0){ red[g][wv][4]=v; red[g][wv][5]=__int_as_float(bi); red[g][wv][6]=e2; }
        __syncthreads();                           // B5: argmax partials visible
        float va = red[g][0][4], vb = red[g][1][4];
        int   ia = __float_as_int(red[g][0][5]), ib = __float_as_int(red[g][1][5]);
        float s2a = red[g][0][6], s2b = red[g][1][6];
        float m2; int ptr;
        if (va > vb || (va == vb && ia < ib)){ m2 = va; ptr = ia; } else { m2 = vb; ptr = ib; }
        float sum2 = fmaf(s2a, __expf(va - m2), s2b * __expf(vb - m2));
        logp -= logf(sum2);                        // log(max prob) = -log(sum exp(l-m))
        if (jl == 0) out[b*N128 + t] = (float)ptr; // tour_idx as float
        lo0 = s0l[g][ptr];                         // broadcast read; s0l/s1l init-only
        lo1 = s1l[g][ptr];
        // no end-of-step barrier needed: next-step LDS writes are fenced by B1..B5
    }
    if (jl == 0) out[B1024*N128 + b] = logp;
}

extern "C" void kernel_launch(void* const* d_in, const int* in_sizes, int n_in,
                              void* d_out, int out_size, void* d_ws, size_t ws_size,
                              hipStream_t stream)
{
    const float* statc   = (const float*)d_in[0];
    const float* dyn     = (const float*)d_in[1];
    const float* enc_s_w = (const float*)d_in[2];
    const float* enc_s_b = (const float*)d_in[3];
    const float* enc_d_w = (const float*)d_in[4];
    const float* enc_d_b = (const float*)d_in[5];
    const float* x0      = (const float*)d_in[6];
    const float* emb_w   = (const float*)d_in[7];
    const float* emb_b   = (const float*)d_in[8];
    const float* w_ih    = (const float*)d_in[9];
    const float* w_hh    = (const float*)d_in[10];
    const float* b_ih    = (const float*)d_in[11];
    const float* b_hh    = (const float*)d_in[12];
    const float* attn_v  = (const float*)d_in[13];
    const float* attn_W  = (const float*)d_in[14];
    const float* dec_v   = (const float*)d_in[15];
    const float* dec_W   = (const float*)d_in[16];

    float* ws = (float*)d_ws;
    float4* A4 = (float4*)(ws);
    float4* D4 = (float4*)(ws + 512);
    float4* Q4 = (float4*)(ws + 1024);
    float4* G4 = (float4*)(ws + 1536);

    prep_kernel<<<dim3(4), dim3(128), 0, stream>>>(
        enc_s_w, enc_s_b, enc_d_w, enc_d_b, emb_w, emb_b,
        w_ih, b_ih, b_hh, attn_v, attn_W, dec_v, dec_W,
        A4, D4, Q4, G4);

    decode_kernel<<<dim3(B1024/2), dim3(256), 0, stream>>>(
        statc, dyn, x0, w_hh, attn_W,
        A4, D4, Q4, G4, (float*)d_out);
}

// Round 5
// 4155.076 us; speedup vs baseline: 1.3677x; 1.1983x over previous
//
#include <hip/hip_runtime.h>

// DRL4TSP pointer-network decode. B=1024, S=2, D=1, H=128, N=128.
// Rank-collapse algebra: static_enc rank-2+bias, dynamic_enc rank-1+bias =>
// all per-step GEMMs become precomputed H-vectors + w_hh@h, A3@h matvecs +
// two HxN tanh-dot loops.
//
// R3 (resubmitted R4; previous attempt hit GPU-acquisition timeout):
// the R2 kernel was stalled on vector-memory ADDRESS DIVERGENCE: each
// lane read its own 512B-strided w_hh/A3 row => 64 cache lines per wave64
// load, ~65K line-requests/CU/step at the TA. Fix: transpose weights once
// (WT[k][r], AT[k][j]) and flip matvecs to outer-product form so lanes read
// consecutive addresses (4 lines/inst). Weight loads now serve BOTH batches
// in the block. Score tables read from global with uniform index (s_load
// path) instead of LDS broadcasts, freeing the DS pipe.

#define H128 128
#define N128 128
#define B1024 1024

__device__ __forceinline__ float sigmoid_acc(float x){
    return 1.f / (1.f + expf(-x));
}
// branch-free fast tanh; abs err ~2e-7, argmax-safe per R1/R2 margin evidence
__device__ __forceinline__ float tanh_fast(float x){
    float xc = fminf(fmaxf(x, -10.f), 10.f);
    float e  = exp2f(xc * 2.885390081777927f);   // exp(2x): 1 mul + v_exp_f32
    return 1.f - __fdividef(2.f, e + 1.f);
}

// ---------------- prep: fold rank structure into packed tables ----------------
// ws floats: A4[512]@0, D4[512]@512, Q4[512]@1024, G4[1536]@1536,
//            WT[49152]@3072 (w_hh^T: WT[k*384+r]), AT[16384]@52224 (A3^T: AT[k*128+j])
__global__ void prep_kernel(const float* __restrict__ enc_s_w, const float* __restrict__ enc_s_b,
                            const float* __restrict__ enc_d_w, const float* __restrict__ enc_d_b,
                            const float* __restrict__ emb_w,   const float* __restrict__ emb_b,
                            const float* __restrict__ w_ih,    const float* __restrict__ b_ih,
                            const float* __restrict__ b_hh,
                            const float* __restrict__ attn_v,  const float* __restrict__ attn_W,
                            const float* __restrict__ dec_v,   const float* __restrict__ dec_W,
                            float4* __restrict__ A4, float4* __restrict__ D4,
                            float4* __restrict__ Q4, float4* __restrict__ G4)
{
    const int tid = threadIdx.x;
    const int blk = blockIdx.x;
    if (blk < 3){
        const int j = blk*128 + tid;
        const float* w = w_ih + j*H128;
        float a = 0.f, b = 0.f, c = 0.f;
        for (int k = 0; k < H128; ++k){
            float wv = w[k];
            a = fmaf(wv, emb_w[2*k],   a);
            b = fmaf(wv, emb_w[2*k+1], b);
            c = fmaf(wv, emb_b[k],     c);
        }
        G4[j] = make_float4(a, b, c + b_ih[j], b_hh[j]);
    } else {
        const int h = tid;
        const float* aw = attn_W + h*384;
        float u0=0.f, u1=0.f, u2=0.f, c1=0.f;
        for (int k = 0; k < H128; ++k){
            float w = aw[k];
            u0 = fmaf(w, enc_s_w[2*k],   u0);
            u1 = fmaf(w, enc_s_w[2*k+1], u1);
            c1 = fmaf(w, enc_s_b[k],     c1);
        }
        for (int k = 0; k < H128; ++k){
            float w = aw[128+k];
            u2 = fmaf(w, enc_d_w[k], u2);
            c1 = fmaf(w, enc_d_b[k], c1);
        }
        A4[h] = make_float4(u0, u1, u2, attn_v[h]);
        const float* dw = dec_W + h*256;
        float v0=0.f, v1=0.f, c2=0.f, q0=0.f, q1=0.f;
        for (int k = 0; k < H128; ++k){
            float w = dw[k];
            v0 = fmaf(w, enc_s_w[2*k],   v0);
            v1 = fmaf(w, enc_s_w[2*k+1], v1);
            c2 = fmaf(w, enc_s_b[k],     c2);
        }
        for (int k = 0; k < H128; ++k){
            float w = dw[128+k];
            q0 = fmaf(w, enc_s_w[2*k],   q0);
            q1 = fmaf(w, enc_s_w[2*k+1], q1);
            c2 = fmaf(w, enc_s_b[k],     c2);   // ctx bias == enc_s_b (sum attn == 1)
        }
        D4[h] = make_float4(v0, v1, dec_v[h], 0.f);
        Q4[h] = make_float4(q0, q1, c2, c1);
    }
}

// one-time weight transpose: coalesced writes, scattered reads (runs once, ~us)
__global__ void tp_kernel(const float* __restrict__ whh, const float* __restrict__ attnW,
                          float* __restrict__ WT, float* __restrict__ AT)
{
    const int idx = blockIdx.x*256 + threadIdx.x;
    if (idx < 49152){
        const int k = idx / 384, r = idx - k*384;   // WT[k][r] = whh[r][k]
        WT[idx] = whh[r*H128 + k];
    } else {
        const int i2 = idx - 49152;                  // AT[k][j] = attn_W[j][256+k]
        const int k = i2 >> 7, j = i2 & 127;
        AT[i2] = attnW[j*384 + 256 + k];
    }
}

// ---------------- main decode: one block = 2 batches, 256 threads ----------------
__global__ __launch_bounds__(256, 2)
void decode_kernel(const float* __restrict__ statc, const float* __restrict__ dyn,
                   const float* __restrict__ x0,
                   const float* __restrict__ WT, const float* __restrict__ AT,
                   const float4* __restrict__ A4g, const float4* __restrict__ D4g,
                   const float4* __restrict__ Q4g, const float4* __restrict__ G4g,
                   float* __restrict__ out)
{
    __shared__ __align__(16) float hbuf[2][2][H128];   // [pingpong][g][h]
    __shared__ float gpre[2][4][H128];                 // [g][r,z,n_gh,n_gi][j]
    __shared__ __align__(16) float ahl[2][H128], chl[2][H128];
    __shared__ float s0l[2][N128], s1l[2][N128];
    __shared__ float red[2][2][8];

    const int tid = threadIdx.x;
    const int g   = tid >> 7;         // batch within block (for phases 2-4)
    const int jl  = tid & 127;        // h-row / n-column owned by this thread
    const int wv  = (tid >> 6) & 1;   // wave within the g-half
    const int b   = blockIdx.x*2 + g;

    // GRU row assignment (phase 1): thread owns row tid (r/z gates) and,
    // if tid<128, row 256+tid (n gate). Each handles BOTH batches.
    const int  gate1 = tid >> 7;          // 0 = r-rows (0-127), 1 = z-rows (128-255)
    const int  j1    = tid & 127;
    const bool has2  = (tid < 128);
    const float4 Gv1 = G4g[tid];
    const float4 Gv2 = has2 ? G4g[256 + tid] : make_float4(0.f,0.f,0.f,0.f);

    const float4 qv = Q4g[jl];
    const float q0r = qv.x, q1r = qv.y, c2r = qv.z, c1r = qv.w;

    const float s0n = statc[b*256 + jl];
    const float s1n = statc[b*256 + 128 + jl];
    const float d0n = dyn[b*128 + jl];
    s0l[g][jl] = s0n; s1l[g][jl] = s1n;
    hbuf[0][g][jl] = 0.f;
    float hreg = 0.f;
    float l00 = x0[0], l01 = x0[1];   // last_out for batch 0 (all threads track both)
    float l10 = l00,   l11 = l01;     // last_out for batch 1

    float logp = 0.f;
    int cur = 0;
    __syncthreads();

    for (int t = 0; t < N128; ++t){
        // ---- phase 1: gh = w_hh@h via transposed weights, coalesced lanes.
        const float4* h0v = (const float4*)&hbuf[cur][0][0];
        const float4* h1v = (const float4*)&hbuf[cur][1][0];
        const float* pW1 = WT + tid;
        float a10 = 0.f, a11 = 0.f;
        #pragma unroll 4
        for (int k4 = 0; k4 < 32; ++k4){
            float4 h0 = h0v[k4], h1 = h1v[k4];
            float w0 = pW1[(4*k4+0)*384];
            float w1 = pW1[(4*k4+1)*384];
            float w2 = pW1[(4*k4+2)*384];
            float w3 = pW1[(4*k4+3)*384];
            a10 = fmaf(w0,h0.x, fmaf(w1,h0.y, fmaf(w2,h0.z, fmaf(w3,h0.w, a10))));
            a11 = fmaf(w0,h1.x, fmaf(w1,h1.y, fmaf(w2,h1.z, fmaf(w3,h1.w, a11))));
        }
        {
            float gi0 = fmaf(Gv1.x, l00, fmaf(Gv1.y, l01, Gv1.z));
            float gi1 = fmaf(Gv1.x, l10, fmaf(Gv1.y, l11, Gv1.z));
            gpre[0][gate1][j1] = gi0 + (a10 + Gv1.w);
            gpre[1][gate1][j1] = gi1 + (a11 + Gv1.w);
        }
        if (has2){                       // n-gate rows (waves 0-1 only)
            const float* pW2 = WT + 256 + tid;
            float a20 = 0.f, a21 = 0.f;
            #pragma unroll 4
            for (int k4 = 0; k4 < 32; ++k4){
                float4 h0 = h0v[k4], h1 = h1v[k4];
                float w0 = pW2[(4*k4+0)*384];
                float w1 = pW2[(4*k4+1)*384];
                float w2 = pW2[(4*k4+2)*384];
                float w3 = pW2[(4*k4+3)*384];
                a20 = fmaf(w0,h0.x, fmaf(w1,h0.y, fmaf(w2,h0.z, fmaf(w3,h0.w, a20))));
                a21 = fmaf(w0,h1.x, fmaf(w1,h1.y, fmaf(w2,h1.z, fmaf(w3,h1.w, a21))));
            }
            gpre[0][2][tid] = a20 + Gv2.w;
            gpre[1][2][tid] = a21 + Gv2.w;
            gpre[0][3][tid] = fmaf(Gv2.x, l00, fmaf(Gv2.y, l01, Gv2.z));
            gpre[1][3][tid] = fmaf(Gv2.x, l10, fmaf(Gv2.y, l11, Gv2.z));
        }
        __syncthreads();                           // B1: gate partials visible
        // combine: thread (g, jl) computes hnew[g][jl]. libm numerics on h path.
        {
            float r  = sigmoid_acc(gpre[g][0][jl]);
            float z  = sigmoid_acc(gpre[g][1][jl]);
            float nn = tanhf(gpre[g][3][jl] + r * gpre[g][2][jl]);
            float hnew = (1.f - z) * nn + z * hreg;
            hbuf[cur^1][g][jl] = hnew; hreg = hnew;
        }
        __syncthreads();                           // B2: new h visible
        cur ^= 1;
        // ---- phase 2: ah = A3@h + c1, transposed/coalesced
        {
            const float4* hn4 = (const float4*)&hbuf[cur][g][0];
            const float* pA = AT + jl;
            float acc = c1r;
            #pragma unroll 4
            for (int k4 = 0; k4 < 32; ++k4){
                float4 hv = hn4[k4];
                acc = fmaf(pA[(4*k4+0)*128], hv.x, acc);
                acc = fmaf(pA[(4*k4+1)*128], hv.y, acc);
                acc = fmaf(pA[(4*k4+2)*128], hv.z, acc);
                acc = fmaf(pA[(4*k4+3)*128], hv.w, acc);
            }
            ahl[g][jl] = acc;
        }
        __syncthreads();                           // B3: ahl visible
        // ---- phase 3: attention scores (thread = column n); tables via uniform
        // global reads (scalar-load path), ahl via LDS broadcast float4.
        const float4* ah4 = (const float4*)&ahl[g][0];
        float sc = 0.f;
        #pragma unroll 2
        for (int k = 0; k < 32; ++k){
            float4 ah = ah4[k];
            { float4 a = A4g[4*k+0]; float tt = fmaf(a.x,s0n, fmaf(a.y,s1n, fmaf(a.z,d0n, ah.x))); sc = fmaf(tanh_fast(tt), a.w, sc); }
            { float4 a = A4g[4*k+1]; float tt = fmaf(a.x,s0n, fmaf(a.y,s1n, fmaf(a.z,d0n, ah.y))); sc = fmaf(tanh_fast(tt), a.w, sc); }
            { float4 a = A4g[4*k+2]; float tt = fmaf(a.x,s0n, fmaf(a.y,s1n, fmaf(a.z,d0n, ah.z))); sc = fmaf(tanh_fast(tt), a.w, sc); }
            { float4 a = A4g[4*k+3]; float tt = fmaf(a.x,s0n, fmaf(a.y,s1n, fmaf(a.z,d0n, ah.w))); sc = fmaf(tanh_fast(tt), a.w, sc); }
        }
        float mw = sc;
        #pragma unroll
        for (int off = 32; off > 0; off >>= 1) mw = fmaxf(mw, __shfl_xor(mw, off, 64));
        float e  = __expf(sc - mw);
        float se = e, sa = e * s0n, sb = e * s1n;
        #pragma unroll
        for (int off = 32; off > 0; off >>= 1){
            se += __shfl_xor(se, off, 64);
            sa += __shfl_xor(sa, off, 64);
            sb += __shfl_xor(sb, off, 64);
        }
        if ((tid & 63) == 0){ red[g][wv][0]=mw; red[g][wv][1]=se; red[g][wv][2]=sa; red[g][wv][3]=sb; }
        __syncthreads();                           // B4: attn partials visible
        {
            float m0 = red[g][0][0], m1 = red[g][1][0];
            float mm = fmaxf(m0, m1);
            float f0 = __expf(m0 - mm), f1 = __expf(m1 - mm);
            float ssum = fmaf(red[g][0][1], f0, red[g][1][1] * f1);
            float sat  = fmaf(red[g][0][2], f0, red[g][1][2] * f1);
            float sbt  = fmaf(red[g][0][3], f0, red[g][1][3] * f1);
            float cs0 = sat / ssum;
            float cs1 = sbt / ssum;
            chl[g][jl] = fmaf(q0r, cs0, fmaf(q1r, cs1, c2r));   // dec_W2@context fold
        }
        __syncthreads();                           // B5: chl visible
        // ---- phase 4: decoder scores + argmax + logsumexp
        const float4* ch4 = (const float4*)&chl[g][0];
        float lg = 0.f;
        #pragma unroll 2
        for (int k = 0; k < 32; ++k){
            float4 ch = ch4[k];
            { float4 dd = D4g[4*k+0]; float tt = fmaf(dd.x,s0n, fmaf(dd.y,s1n, ch.x)); lg = fmaf(tanh_fast(tt), dd.z, lg); }
            { float4 dd = D4g[4*k+1]; float tt = fmaf(dd.x,s0n, fmaf(dd.y,s1n, ch.y)); lg = fmaf(tanh_fast(tt), dd.z, lg); }
            { float4 dd = D4g[4*k+2]; float tt = fmaf(dd.x,s0n, fmaf(dd.y,s1n, ch.z)); lg = fmaf(tanh_fast(tt), dd.z, lg); }
            { float4 dd = D4g[4*k+3]; float tt = fmaf(dd.x,s0n, fmaf(dd.y,s1n, ch.w)); lg = fmaf(tanh_fast(tt), dd.z, lg); }
        }
        float v = lg; int bi = jl;
        #pragma unroll
        for (int off = 32; off > 0; off >>= 1){   // first-index tie-break == jnp.argmax
            float ov = __shfl_xor(v, off, 64);
            int   oi = __shfl_xor(bi, off, 64);
            if (ov > v || (ov == v && oi < bi)){ v = ov; bi = oi; }
        }
        float e2 = __expf(lg - v);
        #pragma unroll
        for (int off = 32; off > 0; off >>= 1) e2 += __shfl_xor(e2, off, 64);
        if ((tid & 63) == 0){ red[g][wv][4]=v; red[g][wv][5]=__int_as_float(bi); red[g][wv][6]=e2; }
        __syncthreads();                           // B6: argmax partials visible
        // combine for BOTH batches (phase-1 needs both last_outs)
        int ptrs[2];
        #pragma unroll
        for (int gg = 0; gg < 2; ++gg){
            float va = red[gg][0][4], vb = red[gg][1][4];
            int   ia = __float_as_int(red[gg][0][5]), ib = __float_as_int(red[gg][1][5]);
            ptrs[gg] = (va > vb || (va == vb && ia < ib)) ? ia : ib;
        }
        {   // own-batch logp
            float va = red[g][0][4], vb = red[g][1][4];
            int   ia = __float_as_int(red[g][0][5]), ib = __float_as_int(red[g][1][5]);
            float s2a = red[g][0][6], s2b = red[g][1][6];
            float m2; int ptr;
            if (va > vb || (va == vb && ia < ib)){ m2 = va; ptr = ia; } else { m2 = vb; ptr = ib; }
            float sum2 = fmaf(s2a, __expf(va - m2), s2b * __expf(vb - m2));
            logp -= logf(sum2);
            if (jl == 0) out[b*N128 + t] = (float)ptr;
        }
        l00 = s0l[0][ptrs[0]]; l01 = s1l[0][ptrs[0]];
        l10 = s0l[1][ptrs[1]]; l11 = s1l[1][ptrs[1]];
        // next-step LDS writes are fenced by B1..B6; no trailing barrier needed
    }
    if (jl == 0) out[B1024*N128 + b] = logp;
}

extern "C" void kernel_launch(void* const* d_in, const int* in_sizes, int n_in,
                              void* d_out, int out_size, void* d_ws, size_t ws_size,
                              hipStream_t stream)
{
    const float* statc   = (const float*)d_in[0];
    const float* dyn     = (const float*)d_in[1];
    const float* enc_s_w = (const float*)d_in[2];
    const float* enc_s_b = (const float*)d_in[3];
    const float* enc_d_w = (const float*)d_in[4];
    const float* enc_d_b = (const float*)d_in[5];
    const float* x0      = (const float*)d_in[6];
    const float* emb_w   = (const float*)d_in[7];
    const float* emb_b   = (const float*)d_in[8];
    const float* w_ih    = (const float*)d_in[9];
    const float* w_hh    = (const float*)d_in[10];
    const float* b_ih    = (const float*)d_in[11];
    const float* b_hh    = (const float*)d_in[12];
    const float* attn_v  = (const float*)d_in[13];
    const float* attn_W  = (const float*)d_in[14];
    const float* dec_v   = (const float*)d_in[15];
    const float* dec_W   = (const float*)d_in[16];

    float* ws = (float*)d_ws;
    float4* A4 = (float4*)(ws);
    float4* D4 = (float4*)(ws + 512);
    float4* Q4 = (float4*)(ws + 1024);
    float4* G4 = (float4*)(ws + 1536);
    float*  WT = ws + 3072;            // [128][384]
    float*  AT = ws + 3072 + 49152;    // [128][128]

    prep_kernel<<<dim3(4), dim3(128), 0, stream>>>(
        enc_s_w, enc_s_b, enc_d_w, enc_d_b, emb_w, emb_b,
        w_ih, b_ih, b_hh, attn_v, attn_W, dec_v, dec_W,
        A4, D4, Q4, G4);

    tp_kernel<<<dim3(256), dim3(256), 0, stream>>>(w_hh, attn_W, WT, AT);

    decode_kernel<<<dim3(B1024/2), dim3(256), 0, stream>>>(
        statc, dyn, x0, WT, AT,
        A4, D4, Q4, G4, (float*)d_out);
}